// Round 3
// baseline (453.363 us; speedup 1.0000x reference)
//
#include <hip/hip_runtime.h>
#include <math.h>

#define WH 16384

typedef __attribute__((ext_vector_type(8))) short short8;   // 8 bf16 (4 VGPRs) MFMA frag
typedef __attribute__((ext_vector_type(4))) float f32x4;    // MFMA accumulator

__device__ __forceinline__ void atomAddF(float* p, float v) {
    __hip_atomic_fetch_add(p, v, __ATOMIC_RELAXED, __HIP_MEMORY_SCOPE_AGENT);
}
// fp32 -> bf16 round-to-nearest-even (integer trick, 3 VALU)
__device__ __forceinline__ unsigned short f2bf(float x) {
    unsigned u = __float_as_uint(x);
    u += 0x7fff + ((u >> 16) & 1);
    return (unsigned short)(u >> 16);
}
__device__ __forceinline__ float bf2f(unsigned short h) {
    return __uint_as_float(((unsigned)h) << 16);
}

// ---------------- zero workspace (G + s regions; ws is poisoned 0xAA) --------
__global__ void zero_ws_kernel(float* __restrict__ p, int n) {
    int i = blockIdx.x * 256 + threadIdx.x;
    if (i < n) p[i] = 0.f;
}

// ---------------- pass A: G = X X^T via split-bf16 MFMA, + channel sums s ----
// grid (16 kchunks, 16 n, 2 inp), block 256 (4 waves). Each block: 1024 px.
// x = hi + lo (bf16 pair); G += Hh*Hh^T + Hh*Lo^T + Lo*Hh^T + Lo*Lo^T -> 4
// chained mfma_f32_16x16x32_bf16 per 16x16 tile per K=32. G symmetric =>
// immune to any A/B operand-order/transpose convention mistake.
// LDS [64ch][256px] bf16 hi+lo, 16B groups XOR-swizzled by (ch&31) so frag
// ds_read_b128 are 2-way max (free) and staging ds_write_b64 conflict-free.
__global__ __launch_bounds__(256, 2) void gram_kernel(
    const float* __restrict__ xR, const float* __restrict__ xT,
    float* __restrict__ G, float* __restrict__ sv) {
    __shared__ unsigned short shi[16384];  // 32 KB
    __shared__ unsigned short slo[16384];  // 32 KB
    const int t = threadIdx.x, w = t >> 6, lane = t & 63;
    const int n = blockIdx.y, inp = blockIdx.z;
    const float* __restrict__ X = (inp ? xT : xR) + (size_t)n * 64 * WH;
    float* __restrict__ Gout = G + (size_t)(inp * 16 + n) * 4096;
    float* __restrict__ Sout = sv + (size_t)(inp * 16 + n) * 64;
    const int pbase = blockIdx.x << 10;

    f32x4 acc[4];
#pragma unroll
    for (int cb = 0; cb < 4; ++cb) acc[cb] = (f32x4){0.f, 0.f, 0.f, 0.f};
    float srow[16];
#pragma unroll
    for (int i = 0; i < 16; ++i) srow[i] = 0.f;

    const int g2 = lane >> 1, halfo = (lane & 1) << 2;
    const int m15 = lane & 15, q = lane >> 4;

    for (int tile = 0; tile < 4; ++tile) {
        const int p0 = pbase + (tile << 8);
        __syncthreads();  // previous tile's frag reads done
        // stage: wave loads one full 1KB row per instr (perfect coalescing),
        // converts to hi/lo bf16, swizzled ds_write_b64 x2
#pragma unroll
        for (int i = 0; i < 16; ++i) {
            const int r = (i << 2) + w;
            const float4 v = *(const float4*)(X + (size_t)r * WH + p0 + (lane << 2));
            srow[i] += v.x + v.y + v.z + v.w;
            const unsigned short h0 = f2bf(v.x), h1 = f2bf(v.y), h2 = f2bf(v.z), h3 = f2bf(v.w);
            const unsigned short l0 = f2bf(v.x - bf2f(h0)), l1 = f2bf(v.y - bf2f(h1)),
                                 l2 = f2bf(v.z - bf2f(h2)), l3 = f2bf(v.w - bf2f(h3));
            const int a = (r << 8) + ((g2 ^ (r & 31)) << 3) + halfo;
            *(ushort4*)&shi[a] = make_ushort4(h0, h1, h2, h3);
            *(ushort4*)&slo[a] = make_ushort4(l0, l1, l2, l3);
        }
        __syncthreads();
        // compute: wave w owns G row-block w; col-blocks 0..3; A-frag == B-frag[w]
#pragma unroll
        for (int kk = 0; kk < 8; ++kk) {
            short8 bh[4], bl[4];
#pragma unroll
            for (int cb = 0; cb < 4; ++cb) {
                const int ch = (cb << 4) + m15;
                const int off = (ch << 8) + ((((kk << 2) + q) ^ (ch & 31)) << 3);
                bh[cb] = *(const short8*)&shi[off];
                bl[cb] = *(const short8*)&slo[off];
            }
            const short8 ah = bh[w], al = bl[w];
#pragma unroll
            for (int cb = 0; cb < 4; ++cb) {
                acc[cb] = __builtin_amdgcn_mfma_f32_16x16x32_bf16(ah, bh[cb], acc[cb], 0, 0, 0);
                acc[cb] = __builtin_amdgcn_mfma_f32_16x16x32_bf16(ah, bl[cb], acc[cb], 0, 0, 0);
                acc[cb] = __builtin_amdgcn_mfma_f32_16x16x32_bf16(al, bh[cb], acc[cb], 0, 0, 0);
                acc[cb] = __builtin_amdgcn_mfma_f32_16x16x32_bf16(al, bl[cb], acc[cb], 0, 0, 0);
            }
        }
    }
    // epilogue: C/D map (verified m89/m91): col=lane&15, row=quad*4+reg
#pragma unroll
    for (int cb = 0; cb < 4; ++cb)
#pragma unroll
        for (int r = 0; r < 4; ++r)
            atomAddF(&Gout[((w << 4) + (q << 2) + r) * 64 + (cb << 4) + m15], acc[cb][r]);
    // channel sums: wave-wide butterfly then 1 atomic per (wave,row)
#pragma unroll
    for (int i = 0; i < 16; ++i) {
        float v = srow[i];
        for (int m = 32; m >= 1; m >>= 1) v += __shfl_xor(v, m, 64);
        if (lane == 0) atomAddF(&Sout[(i << 2) + w], v);
    }
}

// ------- logits + softmax fused: rs = W G W^T + (Ws)b^T + b(Ws)^T + WH bb^T,
//         softmax over the 128 concatenated rows per column, emit att bf16.
// grid 16 (n), block 256. Logits kept in LDS; one kernel instead of two.
__global__ __launch_bounds__(256) void logits_softmax_kernel(
    const float* __restrict__ WR, const float* __restrict__ bR,
    const float* __restrict__ WT, const float* __restrict__ bT,
    const float* __restrict__ G, const float* __restrict__ sv,
    unsigned short* __restrict__ attb) {
    __shared__ float ldsW[4096];
    __shared__ float ldsWt[4096];
    __shared__ float ldsG[4096];
    __shared__ float ldsL[8192];  // logits [128][64]
    __shared__ float ldsS[64], ldsU[64], ldsMx[64], ldsInv[64];
    const int t = threadIdx.x, n = blockIdx.x;
    for (int inp = 0; inp < 2; ++inp) {
        const float* __restrict__ W = inp ? WT : WR;
        const float* __restrict__ b = inp ? bT : bR;
        const float* __restrict__ Gn = G + (size_t)(inp * 16 + n) * 4096;
        const float* __restrict__ sn = sv + (size_t)(inp * 16 + n) * 64;
        __syncthreads();  // protect LDS reuse across inp iterations
#pragma unroll
        for (int m = 0; m < 16; ++m) {
            const int idx = t + (m << 8);
            const float wv = W[idx];
            ldsW[idx] = wv;
            ldsWt[((idx & 63) << 6) + (idx >> 6)] = wv;
            ldsG[idx] = Gn[idx];
        }
        if (t < 64) ldsS[t] = sn[t];
        __syncthreads();
        if (t < 64) {
            float u = 0.f;
            for (int c = 0; c < 64; ++c) u += ldsW[(t << 6) + c] * ldsS[c];
            ldsU[t] = u;  // u = W s
        }
        const int d = t >> 2, e0 = (t & 3) << 4;
        float a[16];
#pragma unroll
        for (int e = 0; e < 16; ++e) a[e] = 0.f;
        for (int c = 0; c < 64; ++c) {
            const float wv = ldsW[(d << 6) + c];
#pragma unroll
            for (int e = 0; e < 16; ++e) a[e] += wv * ldsG[(c << 6) + e0 + e];
        }
        __syncthreads();
#pragma unroll
        for (int e = 0; e < 16; ++e) ldsG[(d << 6) + e0 + e] = a[e];  // M1 = W G
        __syncthreads();
        float r[16];
#pragma unroll
        for (int e = 0; e < 16; ++e) r[e] = 0.f;
        for (int c = 0; c < 64; ++c) {
            const float m1 = ldsG[(d << 6) + c];
#pragma unroll
            for (int e = 0; e < 16; ++e) r[e] += m1 * ldsWt[(c << 6) + e0 + e];
        }
        const float ud = ldsU[d], bd = b[d];
#pragma unroll
        for (int e = 0; e < 16; ++e) {
            const int ee = e0 + e;
            ldsL[((inp << 6) + d) * 64 + ee] =
                r[e] + ud * b[ee] + bd * ldsU[ee] + 16384.f * bd * b[ee];
        }
    }
    __syncthreads();
    if (t < 64) {  // per-column max & sum over 128 rows
        float mx = -1e30f;
        for (int k = 0; k < 128; ++k) mx = fmaxf(mx, ldsL[(k << 6) + t]);
        float s = 0.f;
        for (int k = 0; k < 128; ++k) s += __expf(ldsL[(k << 6) + t] - mx);
        ldsMx[t] = mx;
        ldsInv[t] = 1.f / s;
    }
    __syncthreads();
    unsigned short* __restrict__ an = attb + (size_t)n * 8192;
#pragma unroll
    for (int i = 0; i < 32; ++i) {
        const int idx = (i << 8) + t;
        const int c = idx & 63;
        an[idx] = f2bf(__expf(ldsL[idx] - ldsMx[c]) * ldsInv[c]);
    }
}

// ---------------- pass B: out[n,c,p] = sum_k att[k][c] * [xR;xT][k][p] ------
// Vector fp32 (4.3 GF ~ 27us VALU ~= 30us HBM floor; MFMA wouldn't pay).
// grid (64 px-blocks of 256, 16 n), block 256. Single stage (X bf16 64KB +
// att bf16 16KB = 80KB LDS, 2 blocks/CU), one barrier, K=128 all-LDS inner
// loop, 8c x 8px register tile (64 FMA per 3 LDS reads).
__global__ __launch_bounds__(256, 2) void outv_kernel(
    const float* __restrict__ xR, const float* __restrict__ xT,
    const unsigned short* __restrict__ attb, float* __restrict__ out) {
    __shared__ unsigned short lx[32768];  // [128 k][256 px] bf16, 64 KB
    __shared__ unsigned short la[8192];   // [128 k][64 c]  bf16, 16 KB
    const int t = threadIdx.x, w = t >> 6, lane = t & 63;
    const int n = blockIdx.y;
    const int p0 = blockIdx.x << 8;
    const float* __restrict__ XR = xR + (size_t)n * 64 * WH;
    const float* __restrict__ XT = xT + (size_t)n * 64 * WH;
    const unsigned short* __restrict__ an = attb + (size_t)n * 8192;

#pragma unroll
    for (int i = 0; i < 32; ++i) {
        const int k = (i << 2) + w;
        const float* __restrict__ X = (k < 64) ? (XR + (size_t)k * WH)
                                               : (XT + (size_t)(k - 64) * WH);
        const float4 v = *(const float4*)(X + p0 + (lane << 2));
        *(ushort4*)&lx[(k << 8) + (lane << 2)] =
            make_ushort4(f2bf(v.x), f2bf(v.y), f2bf(v.z), f2bf(v.w));
    }
    // stage att: 8 iters x 256 threads x 4 ushorts = 8192 (R2 bug: was 4 iters
    // -> rows k>=64 read uninitialized LDS -> NaN)
#pragma unroll
    for (int i = 0; i < 8; ++i) {
        const int idx = (i << 10) + (t << 2);
        *(ushort4*)&la[idx] = *(const ushort4*)&an[idx];
    }
    __syncthreads();

    const int ci = t >> 5;  // c rows 8ci..8ci+7 (broadcast att across 32 lanes)
    const int pj = t & 31;  // px pj*4..+3 and 128+pj*4..+3
    float4 acc0[8], acc1[8];
#pragma unroll
    for (int i = 0; i < 8; ++i) {
        acc0[i] = make_float4(0.f, 0.f, 0.f, 0.f);
        acc1[i] = make_float4(0.f, 0.f, 0.f, 0.f);
    }
#pragma unroll 4
    for (int k = 0; k < 128; ++k) {
        const ushort4 aA = *(const ushort4*)&la[(k << 6) + (ci << 3)];
        const ushort4 aB = *(const ushort4*)&la[(k << 6) + (ci << 3) + 4];
        const float av[8] = {bf2f(aA.x), bf2f(aA.y), bf2f(aA.z), bf2f(aA.w),
                             bf2f(aB.x), bf2f(aB.y), bf2f(aB.z), bf2f(aB.w)};
        const ushort4 x0 = *(const ushort4*)&lx[(k << 8) + (pj << 2)];
        const ushort4 x1 = *(const ushort4*)&lx[(k << 8) + 128 + (pj << 2)];
        const float4 v0 = make_float4(bf2f(x0.x), bf2f(x0.y), bf2f(x0.z), bf2f(x0.w));
        const float4 v1 = make_float4(bf2f(x1.x), bf2f(x1.y), bf2f(x1.z), bf2f(x1.w));
#pragma unroll
        for (int i = 0; i < 8; ++i) {
            acc0[i].x += av[i] * v0.x; acc0[i].y += av[i] * v0.y;
            acc0[i].z += av[i] * v0.z; acc0[i].w += av[i] * v0.w;
            acc1[i].x += av[i] * v1.x; acc1[i].y += av[i] * v1.y;
            acc1[i].z += av[i] * v1.z; acc1[i].w += av[i] * v1.w;
        }
    }
    float* __restrict__ on = out + (size_t)n * 64 * WH + p0;
#pragma unroll
    for (int i = 0; i < 8; ++i) {
        const size_t c = (size_t)((ci << 3) + i) * WH;
        *(float4*)(on + c + (pj << 2)) = acc0[i];
        *(float4*)(on + c + 128 + (pj << 2)) = acc1[i];
    }
}

extern "C" void kernel_launch(void* const* d_in, const int* in_sizes, int n_in,
                              void* d_out, int out_size, void* d_ws, size_t ws_size,
                              hipStream_t stream) {
    const float* xR = (const float*)d_in[0];
    const float* xT = (const float*)d_in[1];
    const float* WR = (const float*)d_in[2];
    const float* bR = (const float*)d_in[3];
    const float* WT = (const float*)d_in[4];
    const float* bT = (const float*)d_in[5];
    float* out = (float*)d_out;

    // ws: G [2][16][4096] f32 | s [2][16][64] f32 | att bf16 [16][128][64]
    float* ws = (float*)d_ws;
    float* G = ws;
    float* sv = ws + 131072;
    unsigned short* attb = (unsigned short*)(ws + 133120);

    zero_ws_kernel<<<520, 256, 0, stream>>>(ws, 133120);
    gram_kernel<<<dim3(16, 16, 2), 256, 0, stream>>>(xR, xT, G, sv);
    logits_softmax_kernel<<<16, 256, 0, stream>>>(WR, bR, WT, bT, G, sv, attb);
    outv_kernel<<<dim3(64, 16), 256, 0, stream>>>(xR, xT, attb, out);
}

// Round 4
// 290.910 us; speedup vs baseline: 1.5584x; 1.5584x over previous
//
#include <hip/hip_runtime.h>
#include <math.h>

#define WH 16384

typedef __attribute__((ext_vector_type(8))) short short8;   // 8 bf16 (4 VGPRs) MFMA frag
typedef __attribute__((ext_vector_type(4))) float f32x4;    // MFMA accumulator

__device__ __forceinline__ void atomAddF(float* p, float v) {
    __hip_atomic_fetch_add(p, v, __ATOMIC_RELAXED, __HIP_MEMORY_SCOPE_AGENT);
}
// fp32 -> bf16 round-to-nearest-even (integer trick)
__device__ __forceinline__ unsigned short f2bf(float x) {
    unsigned u = __float_as_uint(x);
    u += 0x7fff + ((u >> 16) & 1);
    return (unsigned short)(u >> 16);
}
__device__ __forceinline__ float bf2f(unsigned short h) {
    return __uint_as_float(((unsigned)h) << 16);
}

// ---------------- zero workspace (G + s regions; ws is poisoned 0xAA) --------
__global__ void zero_ws_kernel(float* __restrict__ p, int n) {
    int i = blockIdx.x * 256 + threadIdx.x;
    if (i < n) p[i] = 0.f;
}

// ---------------- pass A: G = X X^T via split-bf16 MFMA, + channel sums s ----
// grid (16 kchunks, 16 n, 2 inp), block 256 (4 waves), 1024 px per block.
// x = hi + lo (bf16 pair); G += Hh Hh^T + Hh Lo^T + Lo Hh^T + Lo Lo^T.
// R3 BUG FIXED: `bh[w]` (runtime index into local array) forced the frag
// arrays into scratch memory -> 162us of scratch traffic. Now every fragment
// is a named variable; A-frags are their own ds_reads addressed by w.
__global__ __launch_bounds__(256, 2) void gram_kernel(
    const float* __restrict__ xR, const float* __restrict__ xT,
    float* __restrict__ G, float* __restrict__ sv) {
    __shared__ unsigned short shi[16384];  // 32 KB
    __shared__ unsigned short slo[16384];  // 32 KB
    const int t = threadIdx.x, w = t >> 6, lane = t & 63;
    const int n = blockIdx.y, inp = blockIdx.z;
    const float* __restrict__ X = (inp ? xT : xR) + (size_t)n * 64 * WH;
    float* __restrict__ Gout = G + (size_t)(inp * 16 + n) * 4096;
    float* __restrict__ Sout = sv + (size_t)(inp * 16 + n) * 64;
    const int pbase = blockIdx.x << 10;

    f32x4 acc0 = {0.f, 0.f, 0.f, 0.f}, acc1 = acc0, acc2 = acc0, acc3 = acc0;
    float srow[16];
#pragma unroll
    for (int i = 0; i < 16; ++i) srow[i] = 0.f;

    const int g2 = lane >> 1, halfo = (lane & 1) << 2;
    const int m15 = lane & 15, q = lane >> 4;
    // per-cb channel + swizzle-base constants (all compile-time-ish scalars)
    const int cha = (w << 4) + m15;
    const int ch0 = m15, ch1 = 16 + m15, ch2 = 32 + m15, ch3 = 48 + m15;

    for (int tile = 0; tile < 4; ++tile) {
        const int p0 = pbase + (tile << 8);
        __syncthreads();  // previous tile's frag reads done
        // stage: each wave loads one full 1KB row per instr (perfect
        // coalescing), converts to hi/lo bf16, swizzled ds_write_b64 x2
#pragma unroll
        for (int i = 0; i < 16; ++i) {
            const int r = (i << 2) + w;
            const float4 v = *(const float4*)(X + (size_t)r * WH + p0 + (lane << 2));
            srow[i] += v.x + v.y + v.z + v.w;
            const unsigned short h0 = f2bf(v.x), h1 = f2bf(v.y), h2 = f2bf(v.z), h3 = f2bf(v.w);
            const unsigned short l0 = f2bf(v.x - bf2f(h0)), l1 = f2bf(v.y - bf2f(h1)),
                                 l2 = f2bf(v.z - bf2f(h2)), l3 = f2bf(v.w - bf2f(h3));
            const int a = (r << 8) + ((g2 ^ (r & 31)) << 3) + halfo;
            *(ushort4*)&shi[a] = make_ushort4(h0, h1, h2, h3);
            *(ushort4*)&slo[a] = make_ushort4(l0, l1, l2, l3);
        }
        __syncthreads();
        // compute: wave w owns G row-block w; col-blocks 0..3
#pragma unroll
        for (int kk = 0; kk < 8; ++kk) {
            const int grp = (kk << 2) + q;
            const int offa = (cha << 8) + ((grp ^ (cha & 31)) << 3);
            const int off0 = (ch0 << 8) + ((grp ^ (ch0 & 31)) << 3);
            const int off1 = (ch1 << 8) + ((grp ^ (ch1 & 31)) << 3);
            const int off2 = (ch2 << 8) + ((grp ^ (ch2 & 31)) << 3);
            const int off3 = (ch3 << 8) + ((grp ^ (ch3 & 31)) << 3);
            const short8 ah = *(const short8*)&shi[offa];
            const short8 al = *(const short8*)&slo[offa];
            const short8 bh0 = *(const short8*)&shi[off0], bl0 = *(const short8*)&slo[off0];
            const short8 bh1 = *(const short8*)&shi[off1], bl1 = *(const short8*)&slo[off1];
            const short8 bh2 = *(const short8*)&shi[off2], bl2 = *(const short8*)&slo[off2];
            const short8 bh3 = *(const short8*)&shi[off3], bl3 = *(const short8*)&slo[off3];
            acc0 = __builtin_amdgcn_mfma_f32_16x16x32_bf16(ah, bh0, acc0, 0, 0, 0);
            acc0 = __builtin_amdgcn_mfma_f32_16x16x32_bf16(ah, bl0, acc0, 0, 0, 0);
            acc0 = __builtin_amdgcn_mfma_f32_16x16x32_bf16(al, bh0, acc0, 0, 0, 0);
            acc0 = __builtin_amdgcn_mfma_f32_16x16x32_bf16(al, bl0, acc0, 0, 0, 0);
            acc1 = __builtin_amdgcn_mfma_f32_16x16x32_bf16(ah, bh1, acc1, 0, 0, 0);
            acc1 = __builtin_amdgcn_mfma_f32_16x16x32_bf16(ah, bl1, acc1, 0, 0, 0);
            acc1 = __builtin_amdgcn_mfma_f32_16x16x32_bf16(al, bh1, acc1, 0, 0, 0);
            acc1 = __builtin_amdgcn_mfma_f32_16x16x32_bf16(al, bl1, acc1, 0, 0, 0);
            acc2 = __builtin_amdgcn_mfma_f32_16x16x32_bf16(ah, bh2, acc2, 0, 0, 0);
            acc2 = __builtin_amdgcn_mfma_f32_16x16x32_bf16(ah, bl2, acc2, 0, 0, 0);
            acc2 = __builtin_amdgcn_mfma_f32_16x16x32_bf16(al, bh2, acc2, 0, 0, 0);
            acc2 = __builtin_amdgcn_mfma_f32_16x16x32_bf16(al, bl2, acc2, 0, 0, 0);
            acc3 = __builtin_amdgcn_mfma_f32_16x16x32_bf16(ah, bh3, acc3, 0, 0, 0);
            acc3 = __builtin_amdgcn_mfma_f32_16x16x32_bf16(ah, bl3, acc3, 0, 0, 0);
            acc3 = __builtin_amdgcn_mfma_f32_16x16x32_bf16(al, bh3, acc3, 0, 0, 0);
            acc3 = __builtin_amdgcn_mfma_f32_16x16x32_bf16(al, bl3, acc3, 0, 0, 0);
        }
    }
    // epilogue: C/D map (verified m89/m91): col=lane&15, row=quad*4+reg
    const int rb = (w << 4) + (q << 2);
#pragma unroll
    for (int r = 0; r < 4; ++r) {
        atomAddF(&Gout[(rb + r) * 64 + 0 + m15], acc0[r]);
        atomAddF(&Gout[(rb + r) * 64 + 16 + m15], acc1[r]);
        atomAddF(&Gout[(rb + r) * 64 + 32 + m15], acc2[r]);
        atomAddF(&Gout[(rb + r) * 64 + 48 + m15], acc3[r]);
    }
    // channel sums: wave-wide butterfly then 1 atomic per (wave,row)
#pragma unroll
    for (int i = 0; i < 16; ++i) {
        float v = srow[i];
        for (int m = 32; m >= 1; m >>= 1) v += __shfl_xor(v, m, 64);
        if (lane == 0) atomAddF(&Sout[(i << 2) + w], v);
    }
}

// ------- logits + softmax fused: rs = W G W^T + (Ws)b^T + b(Ws)^T + WH bb^T,
//         softmax over the 128 concatenated rows per column, emit att bf16.
__global__ __launch_bounds__(256) void logits_softmax_kernel(
    const float* __restrict__ WR, const float* __restrict__ bR,
    const float* __restrict__ WT, const float* __restrict__ bT,
    const float* __restrict__ G, const float* __restrict__ sv,
    unsigned short* __restrict__ attb) {
    __shared__ float ldsW[4096];
    __shared__ float ldsWt[4096];
    __shared__ float ldsG[4096];
    __shared__ float ldsL[8192];  // logits [128][64]
    __shared__ float ldsS[64], ldsU[64], ldsMx[64], ldsInv[64];
    const int t = threadIdx.x, n = blockIdx.x;
    for (int inp = 0; inp < 2; ++inp) {
        const float* __restrict__ W = inp ? WT : WR;
        const float* __restrict__ b = inp ? bT : bR;
        const float* __restrict__ Gn = G + (size_t)(inp * 16 + n) * 4096;
        const float* __restrict__ sn = sv + (size_t)(inp * 16 + n) * 64;
        __syncthreads();  // protect LDS reuse across inp iterations
#pragma unroll
        for (int m = 0; m < 16; ++m) {
            const int idx = t + (m << 8);
            const float wv = W[idx];
            ldsW[idx] = wv;
            ldsWt[((idx & 63) << 6) + (idx >> 6)] = wv;
            ldsG[idx] = Gn[idx];
        }
        if (t < 64) ldsS[t] = sn[t];
        __syncthreads();
        if (t < 64) {
            float u = 0.f;
            for (int c = 0; c < 64; ++c) u += ldsW[(t << 6) + c] * ldsS[c];
            ldsU[t] = u;  // u = W s
        }
        const int d = t >> 2, e0 = (t & 3) << 4;
        float a[16];
#pragma unroll
        for (int e = 0; e < 16; ++e) a[e] = 0.f;
        for (int c = 0; c < 64; ++c) {
            const float wv = ldsW[(d << 6) + c];
#pragma unroll
            for (int e = 0; e < 16; ++e) a[e] += wv * ldsG[(c << 6) + e0 + e];
        }
        __syncthreads();
#pragma unroll
        for (int e = 0; e < 16; ++e) ldsG[(d << 6) + e0 + e] = a[e];  // M1 = W G
        __syncthreads();
        float r[16];
#pragma unroll
        for (int e = 0; e < 16; ++e) r[e] = 0.f;
        for (int c = 0; c < 64; ++c) {
            const float m1 = ldsG[(d << 6) + c];
#pragma unroll
            for (int e = 0; e < 16; ++e) r[e] += m1 * ldsWt[(c << 6) + e0 + e];
        }
        const float ud = ldsU[d], bd = b[d];
#pragma unroll
        for (int e = 0; e < 16; ++e) {
            const int ee = e0 + e;
            ldsL[((inp << 6) + d) * 64 + ee] =
                r[e] + ud * b[ee] + bd * ldsU[ee] + 16384.f * bd * b[ee];
        }
    }
    __syncthreads();
    if (t < 64) {  // per-column max & sum over 128 rows
        float mx = -1e30f;
        for (int k = 0; k < 128; ++k) mx = fmaxf(mx, ldsL[(k << 6) + t]);
        float s = 0.f;
        for (int k = 0; k < 128; ++k) s += __expf(ldsL[(k << 6) + t] - mx);
        ldsMx[t] = mx;
        ldsInv[t] = 1.f / s;
    }
    __syncthreads();
    unsigned short* __restrict__ an = attb + (size_t)n * 8192;
#pragma unroll
    for (int i = 0; i < 32; ++i) {
        const int idx = (i << 8) + t;
        const int c = idx & 63;
        an[idx] = f2bf(__expf(ldsL[idx] - ldsMx[c]) * ldsInv[c]);
    }
}

// ---------------- pass B: out[n,c,p] = sum_k att[k][c] * [xR;xT][k][p] ------
// grid (64 px-blocks of 256, 16 n), block 256. Single stage (X bf16 64KB +
// att bf16 16KB = 80KB LDS, 2 blocks/CU), one barrier, K=128 all-LDS inner
// loop, 8c x 8px register tile. All accumulators/broadcast values are NAMED
// variables (no local arrays anywhere -> no possible scratch demotion).
#define FMA4(acc, s, v)        \
    acc.x += (s) * (v).x;      \
    acc.y += (s) * (v).y;      \
    acc.z += (s) * (v).z;      \
    acc.w += (s) * (v).w
__global__ __launch_bounds__(256, 2) void outv_kernel(
    const float* __restrict__ xR, const float* __restrict__ xT,
    const unsigned short* __restrict__ attb, float* __restrict__ out) {
    __shared__ unsigned short lx[32768];  // [128 k][256 px] bf16, 64 KB
    __shared__ unsigned short la[8192];   // [128 k][64 c]  bf16, 16 KB
    const int t = threadIdx.x, w = t >> 6, lane = t & 63;
    const int n = blockIdx.y;
    const int p0 = blockIdx.x << 8;
    const float* __restrict__ XR = xR + (size_t)n * 64 * WH;
    const float* __restrict__ XT = xT + (size_t)n * 64 * WH;
    const unsigned short* __restrict__ an = attb + (size_t)n * 8192;

#pragma unroll
    for (int i = 0; i < 32; ++i) {
        const int k = (i << 2) + w;
        const float* __restrict__ X = (k < 64) ? (XR + (size_t)k * WH)
                                               : (XT + (size_t)(k - 64) * WH);
        const float4 v = *(const float4*)(X + p0 + (lane << 2));
        *(ushort4*)&lx[(k << 8) + (lane << 2)] =
            make_ushort4(f2bf(v.x), f2bf(v.y), f2bf(v.z), f2bf(v.w));
    }
#pragma unroll
    for (int i = 0; i < 8; ++i) {
        const int idx = (i << 10) + (t << 2);
        *(ushort4*)&la[idx] = *(const ushort4*)&an[idx];
    }
    __syncthreads();

    const int ci = t >> 5;  // c rows 8ci..8ci+7 (att broadcast across 32 lanes)
    const int pj = t & 31;  // px pj*4..+3 and 128+pj*4..+3
    const float4 z4 = make_float4(0.f, 0.f, 0.f, 0.f);
    float4 c00 = z4, c01 = z4, c02 = z4, c03 = z4, c04 = z4, c05 = z4, c06 = z4, c07 = z4;
    float4 c10 = z4, c11 = z4, c12 = z4, c13 = z4, c14 = z4, c15 = z4, c16 = z4, c17 = z4;
#pragma unroll 4
    for (int k = 0; k < 128; ++k) {
        const ushort4 aA = *(const ushort4*)&la[(k << 6) + (ci << 3)];
        const ushort4 aB = *(const ushort4*)&la[(k << 6) + (ci << 3) + 4];
        const ushort4 x0 = *(const ushort4*)&lx[(k << 8) + (pj << 2)];
        const ushort4 x1 = *(const ushort4*)&lx[(k << 8) + 128 + (pj << 2)];
        const float4 v0 = make_float4(bf2f(x0.x), bf2f(x0.y), bf2f(x0.z), bf2f(x0.w));
        const float4 v1 = make_float4(bf2f(x1.x), bf2f(x1.y), bf2f(x1.z), bf2f(x1.w));
        const float a0 = bf2f(aA.x), a1 = bf2f(aA.y), a2 = bf2f(aA.z), a3 = bf2f(aA.w);
        const float a4 = bf2f(aB.x), a5 = bf2f(aB.y), a6 = bf2f(aB.z), a7 = bf2f(aB.w);
        FMA4(c00, a0, v0); FMA4(c10, a0, v1);
        FMA4(c01, a1, v0); FMA4(c11, a1, v1);
        FMA4(c02, a2, v0); FMA4(c12, a2, v1);
        FMA4(c03, a3, v0); FMA4(c13, a3, v1);
        FMA4(c04, a4, v0); FMA4(c14, a4, v1);
        FMA4(c05, a5, v0); FMA4(c15, a5, v1);
        FMA4(c06, a6, v0); FMA4(c16, a6, v1);
        FMA4(c07, a7, v0); FMA4(c17, a7, v1);
    }
    float* __restrict__ on = out + (size_t)n * 64 * WH + p0;
    const int cb = ci << 3;
    const int po = pj << 2;
    *(float4*)(on + (size_t)(cb + 0) * WH + po) = c00;
    *(float4*)(on + (size_t)(cb + 1) * WH + po) = c01;
    *(float4*)(on + (size_t)(cb + 2) * WH + po) = c02;
    *(float4*)(on + (size_t)(cb + 3) * WH + po) = c03;
    *(float4*)(on + (size_t)(cb + 4) * WH + po) = c04;
    *(float4*)(on + (size_t)(cb + 5) * WH + po) = c05;
    *(float4*)(on + (size_t)(cb + 6) * WH + po) = c06;
    *(float4*)(on + (size_t)(cb + 7) * WH + po) = c07;
    *(float4*)(on + (size_t)(cb + 0) * WH + 128 + po) = c10;
    *(float4*)(on + (size_t)(cb + 1) * WH + 128 + po) = c11;
    *(float4*)(on + (size_t)(cb + 2) * WH + 128 + po) = c12;
    *(float4*)(on + (size_t)(cb + 3) * WH + 128 + po) = c13;
    *(float4*)(on + (size_t)(cb + 4) * WH + 128 + po) = c14;
    *(float4*)(on + (size_t)(cb + 5) * WH + 128 + po) = c15;
    *(float4*)(on + (size_t)(cb + 6) * WH + 128 + po) = c16;
    *(float4*)(on + (size_t)(cb + 7) * WH + 128 + po) = c17;
}

extern "C" void kernel_launch(void* const* d_in, const int* in_sizes, int n_in,
                              void* d_out, int out_size, void* d_ws, size_t ws_size,
                              hipStream_t stream) {
    const float* xR = (const float*)d_in[0];
    const float* xT = (const float*)d_in[1];
    const float* WR = (const float*)d_in[2];
    const float* bR = (const float*)d_in[3];
    const float* WT = (const float*)d_in[4];
    const float* bT = (const float*)d_in[5];
    float* out = (float*)d_out;

    // ws: G [2][16][4096] f32 | s [2][16][64] f32 | att bf16 [16][128][64]
    float* ws = (float*)d_ws;
    float* G = ws;
    float* sv = ws + 131072;
    unsigned short* attb = (unsigned short*)(ws + 133120);

    zero_ws_kernel<<<520, 256, 0, stream>>>(ws, 133120);
    gram_kernel<<<dim3(16, 16, 2), 256, 0, stream>>>(xR, xT, G, sv);
    logits_softmax_kernel<<<16, 256, 0, stream>>>(WR, bR, WT, bT, G, sv, attb);
    outv_kernel<<<dim3(64, 16), 256, 0, stream>>>(xR, xT, attb, out);
}